// Round 5
// baseline (169.511 us; speedup 1.0000x reference)
//
#include <hip/hip_runtime.h>
#include <stddef.h>

#define NN 2048
#define DIN 128
#define HD 32

typedef __attribute__((ext_vector_type(8))) short short8;
typedef __attribute__((ext_vector_type(4))) float f32x4;

constexpr float SLOPE = 0.2f;
constexpr float LC = 7.2134752044448170f; // log2(e)/TEMP

__device__ __forceinline__ unsigned int pack_rne(float a, float b){
    unsigned int xa = __float_as_uint(a), xb = __float_as_uint(b);
    unsigned int ra = (xa + 0x7fffu + ((xa >> 16) & 1u)) >> 16;
    unsigned int rb = (xb + 0x7fffu + ((xb >> 16) & 1u)) >> 16;
    return ra | (rb << 16);
}

// ---- kWhScore: h-tile in LDS once; scores via h.(W a) f32-exact; Wh GEMM with
// ---- W from broadcast VMEM (registers, no LDS reads); writes whT bf16 [bh][o][m].
__global__ __launch_bounds__(256) void kWhScore(const float* __restrict__ hg,
                                                const float* __restrict__ Wg,
                                                const float* __restrict__ ag,
                                                unsigned short* __restrict__ whT,
                                                float* __restrict__ sSrc,
                                                float* __restrict__ sDst,
                                                float* __restrict__ maxPart)
{
    __shared__ float Hl[32][132];   // pad 4: b128 rows 528 B, 16B-aligned
    __shared__ float wal[8][128];   // [hh*2+d][i]
    __shared__ float al[256];
    const int t = threadIdx.x;
    const int b = blockIdx.x >> 6;
    const int tile = blockIdx.x & 63;
    const int n0 = tile*32;
    #pragma unroll
    for (int ii = 0; ii < 4; ++ii){
        const int idx = t + 256*ii;
        const int r = idx >> 5, c4 = idx & 31;
        *(float4*)&Hl[r][c4*4] = *(const float4*)&hg[((size_t)b*NN + n0 + r)*DIN + c4*4];
    }
    al[t] = ag[t];
    __syncthreads();
    #pragma unroll
    for (int jj = 0; jj < 4; ++jj){
        const int idx = t + 256*jj;
        const int combo = idx >> 7, i = idx & 127;
        const int hh = combo >> 1, d = combo & 1;
        const float* wrow = &Wg[hh*4096 + i*32];
        const float* av = &al[hh*64 + d*32];
        float s = 0.f;
        #pragma unroll
        for (int q = 0; q < 8; ++q){
            const float4 w = *(const float4*)&wrow[q*4];
            s += w.x*av[q*4] + w.y*av[q*4+1] + w.z*av[q*4+2] + w.w*av[q*4+3];
        }
        wal[combo][i] = s;
    }
    __syncthreads();
    {   // scores: wave = head; lanes 0-31 src, 32-63 dst
        const int combo = t >> 5, nl = t & 31;
        const int hh = combo >> 1, d = combo & 1;
        float s = 0.f;
        #pragma unroll
        for (int q = 0; q < 32; ++q){
            const float4 hv = *(const float4*)&Hl[nl][q*4];
            const float4 wv = *(const float4*)&wal[combo][q*4];
            s += hv.x*wv.x + hv.y*wv.y + hv.z*wv.z + hv.w*wv.w;
        }
        const int bh = b*4 + hh;
        if (d == 0) sSrc[bh*NN + n0 + nl] = s;
        else {
            sDst[bh*NN + n0 + nl] = s;
            float lm = s;
            #pragma unroll
            for (int off = 1; off < 32; off <<= 1) lm = fmaxf(lm, __shfl_xor(lm, off));
            if (nl == 0) maxPart[bh*64 + tile] = lm;
        }
    }
    // Wh GEMM: thread = (row nl, 4-o group og), all 4 heads; W via broadcast loads
    const int og = t >> 5, nl = t & 31;
    const int o0 = og*4;
    float acc[16];
    #pragma unroll
    for (int k = 0; k < 16; ++k) acc[k] = 0.f;
    for (int kc = 0; kc < 16; ++kc){
        const float4 hA = *(const float4*)&Hl[nl][kc*8];
        const float4 hB = *(const float4*)&Hl[nl][kc*8+4];
        const float hreg[8] = {hA.x,hA.y,hA.z,hA.w,hB.x,hB.y,hB.z,hB.w};
        #pragma unroll
        for (int hh = 0; hh < 4; ++hh){
            #pragma unroll
            for (int i8 = 0; i8 < 8; ++i8){
                const float4 w = *(const float4*)&Wg[hh*4096 + (kc*8+i8)*32 + o0];
                acc[hh*4+0] = fmaf(hreg[i8], w.x, acc[hh*4+0]);
                acc[hh*4+1] = fmaf(hreg[i8], w.y, acc[hh*4+1]);
                acc[hh*4+2] = fmaf(hreg[i8], w.z, acc[hh*4+2]);
                acc[hh*4+3] = fmaf(hreg[i8], w.w, acc[hh*4+3]);
            }
        }
    }
    #pragma unroll
    for (int hh = 0; hh < 4; ++hh){
        #pragma unroll
        for (int j = 0; j < 4; ++j){
            const unsigned int x = __float_as_uint(acc[hh*4+j]);
            whT[((size_t)(b*4+hh)*32 + o0 + j)*NN + n0 + nl] =
                (unsigned short)((x + 0x7fffu + ((x>>16)&1u)) >> 16);
        }
    }
}

// ---- kMaxR: collapse 64 max partials per bh to one scalar ------------------
__global__ void kMaxR(const float* __restrict__ maxPart, float* __restrict__ maxFull){
    const int t = threadIdx.x;
    if (t < 16){
        float m = maxPart[t*64];
        for (int i = 1; i < 64; ++i) m = fmaxf(m, maxPart[t*64+i]);
        maxFull[t] = m;
    }
}

// ---- kAttnM: fused softmax (known max) + PV via MFMA; whT staged by copy ---
__global__ __launch_bounds__(256) void kAttnM(const unsigned short* __restrict__ whT,
                                              const float* __restrict__ sSrc,
                                              const float* __restrict__ sDst,
                                              const float* __restrict__ maxFull,
                                              float* __restrict__ invZ,
                                              unsigned short* __restrict__ hcb)
{
    __shared__ unsigned short WtT[32][136];
    __shared__ float sdl[128];
    const int t = threadIdx.x;
    const int wv = t >> 6, lane = t & 63;
    const int q = lane >> 4, c = lane & 15;
    const int bh = blockIdx.x >> 5;
    const int n0 = (blockIdx.x & 31)*64 + wv*16;
    const int b = bh >> 2, hh = bh & 3;
    const float mx = maxFull[bh];
    const float ssrc = sSrc[bh*NN + n0 + c];
    const float q0 = ssrc + mx;
    const float R = fmaxf(q0, SLOPE*q0) * LC;
    const float a1 = ssrc*LC - R;
    const float a2 = SLOPE*LC*ssrc - R;
    f32x4 acc0 = {0.f,0.f,0.f,0.f}, acc1 = {0.f,0.f,0.f,0.f};
    float Zp = 0.f;
    for (int mt = 0; mt < 16; ++mt){
        const int mb = mt*128;
        __syncthreads();
        #pragma unroll
        for (int ps = 0; ps < 2; ++ps){
            const int o = ps*16 + (t >> 4);
            const int mo = (t & 15)*8;
            *(short8*)&WtT[o][mo] = *(const short8*)&whT[((size_t)bh*32 + o)*NN + mb + mo];
        }
        if (t < 128) sdl[t] = LC * sDst[bh*NN + mb + t];
        __syncthreads();
        #pragma unroll
        for (int ks = 0; ks < 4; ++ks){
            const int m8 = ks*32 + q*8;
            float p[8];
            #pragma unroll
            for (int j = 0; j < 8; ++j){
                const float u = sdl[m8 + j];
                p[j] = exp2f(fmaxf(a1 + u, fmaf(SLOPE, u, a2)));
                Zp += p[j];
            }
            short8 aF;
            #pragma unroll
            for (int j = 0; j < 8; j += 2){
                ((unsigned int*)&aF)[j>>1] = (__float_as_uint(p[j]) >> 16)
                                           | (__float_as_uint(p[j+1]) & 0xffff0000u);
            }
            const short8 bF0 = *(const short8*)&WtT[c][m8];
            const short8 bF1 = *(const short8*)&WtT[16 + c][m8];
            acc0 = __builtin_amdgcn_mfma_f32_16x16x32_bf16(aF, bF0, acc0, 0, 0, 0);
            acc1 = __builtin_amdgcn_mfma_f32_16x16x32_bf16(aF, bF1, acc1, 0, 0, 0);
        }
    }
    Zp += __shfl_xor(Zp, 16);
    Zp += __shfl_xor(Zp, 32);
    const float iz = 1.0f / Zp;
    if (q == 0) invZ[bh*NN + n0 + c] = iz;
    #pragma unroll
    for (int reg = 0; reg < 4; ++reg){
        const int row = q*4 + reg;
        const float izr = __shfl(iz, row);
        const size_t base = ((size_t)b*NN + n0 + row)*128 + hh*32;
        hcb[base + c]      = (unsigned short)((pack_rne(acc0[reg]*izr, 0.f)) & 0xffffu);
        hcb[base + 16 + c] = (unsigned short)((pack_rne(acc1[reg]*izr, 0.f)) & 0xffffu);
    }
}

// ---- kAlpha: alpha.mean over heads -> out1 (f32) ---------------------------
__global__ __launch_bounds__(256) void kAlpha(const float* __restrict__ sSrc,
                                              const float* __restrict__ sDst,
                                              const float* __restrict__ maxFull,
                                              const float* __restrict__ invZ,
                                              float* __restrict__ out1)
{
    __shared__ float sdl[4][NN];
    const int t = threadIdx.x;
    const int b = blockIdx.x >> 9;
    const int n0 = (blockIdx.x & 511) * 4;
    for (int i = t; i < 4*NN; i += 256)
        sdl[i >> 11][i & (NN-1)] = LC * sDst[(size_t)(b*4 + (i>>11))*NN + (i & (NN-1))];
    __syncthreads();
    float a1[4][4], a2[4][4], cf[4][4];
    #pragma unroll
    for (int hh = 0; hh < 4; ++hh){
        const float mx = maxFull[b*4+hh];
        #pragma unroll
        for (int rr = 0; rr < 4; ++rr){
            const int bhn = (b*4+hh)*NN + n0 + rr;
            const float ss = sSrc[bhn];
            const float q0 = ss + mx;
            const float R = fmaxf(q0, SLOPE*q0)*LC;
            a1[rr][hh] = ss*LC - R;
            a2[rr][hh] = SLOPE*LC*ss - R;
            cf[rr][hh] = 0.25f * invZ[bhn];
        }
    }
    for (int mb = 0; mb < NN; mb += 256){
        const int m = mb + t;
        const float u0 = sdl[0][m], u1 = sdl[1][m], u2 = sdl[2][m], u3 = sdl[3][m];
        #pragma unroll
        for (int rr = 0; rr < 4; ++rr){
            float v;
            v  = cf[rr][0]*exp2f(fmaxf(a1[rr][0]+u0, fmaf(SLOPE, u0, a2[rr][0])));
            v += cf[rr][1]*exp2f(fmaxf(a1[rr][1]+u1, fmaf(SLOPE, u1, a2[rr][1])));
            v += cf[rr][2]*exp2f(fmaxf(a1[rr][2]+u2, fmaf(SLOPE, u2, a2[rr][2])));
            v += cf[rr][3]*exp2f(fmaxf(a1[rr][3]+u3, fmaf(SLOPE, u3, a2[rr][3])));
            out1[((size_t)b*NN + n0 + rr)*NN + m] = v;
        }
    }
}

// ---- kMergeM: out0 = hcb(bf16) @ mw^T(bf16) + bias via MFMA ----------------
__global__ __launch_bounds__(256) void kMergeM(const unsigned short* __restrict__ hcb,
                                               const float* __restrict__ mw,
                                               const float* __restrict__ mbv,
                                               float* __restrict__ out0)
{
    __shared__ unsigned short mwb[128][136];
    const int t = threadIdx.x;
    const int wv = t >> 6, lane = t & 63;
    const int q = lane >> 4, c = lane & 15;
    for (int i = t; i < 128*64; i += 256){
        const int j = i >> 6, k2 = i & 63;
        const float2 v = *(const float2*)&mw[j*128 + k2*2];
        *(unsigned int*)&mwb[j][k2*2] = pack_rne(v.x, v.y);
    }
    __syncthreads();
    const int row0 = blockIdx.x*64 + wv*16;
    f32x4 acc[8];
    #pragma unroll
    for (int ot = 0; ot < 8; ++ot) acc[ot] = (f32x4){0.f,0.f,0.f,0.f};
    #pragma unroll
    for (int ks = 0; ks < 4; ++ks){
        const short8 aF = *(const short8*)&hcb[((size_t)row0 + c)*128 + ks*32 + q*8];
        #pragma unroll
        for (int ot = 0; ot < 8; ++ot){
            const short8 bF = *(const short8*)&mwb[ot*16 + c][ks*32 + q*8];
            acc[ot] = __builtin_amdgcn_mfma_f32_16x16x32_bf16(aF, bF, acc[ot], 0, 0, 0);
        }
    }
    #pragma unroll
    for (int ot = 0; ot < 8; ++ot){
        const int col = ot*16 + c;
        const float bias = mbv[col];
        #pragma unroll
        for (int reg = 0; reg < 4; ++reg){
            const size_t row = (size_t)row0 + q*4 + reg;
            out0[row*128 + col] = acc[ot][reg] + bias;
        }
    }
}

extern "C" void kernel_launch(void* const* d_in, const int* in_sizes, int n_in,
                              void* d_out, int out_size, void* d_ws, size_t ws_size,
                              hipStream_t stream)
{
    const float* hg  = (const float*)d_in[0];
    const float* Wg  = (const float*)d_in[1];
    const float* ag  = (const float*)d_in[2];
    const float* mw  = (const float*)d_in[3];
    const float* mbv = (const float*)d_in[4];
    float* out0 = (float*)d_out;
    float* out1 = out0 + (size_t)4*NN*128;

    float* ws      = (float*)d_ws;
    float* sSrc    = ws;                      //  32,768 f32
    float* sDst    = sSrc + 32768;            //  32,768
    float* maxPart = sDst + 32768;            //   1,024
    float* maxFull = maxPart + 1024;          //      16
    float* invZ    = maxFull + 16;            //  32,768
    unsigned short* whT = (unsigned short*)(invZ + 32768);   // 1,048,576 bf16
    unsigned short* hcb = whT + (size_t)16*32*NN;            // 1,048,576 bf16

    hipLaunchKernelGGL(kWhScore, dim3(256),  dim3(256), 0, stream, hg, Wg, ag, whT, sSrc, sDst, maxPart);
    hipLaunchKernelGGL(kMaxR,    dim3(1),    dim3(64),  0, stream, maxPart, maxFull);
    hipLaunchKernelGGL(kAttnM,   dim3(512),  dim3(256), 0, stream, whT, sSrc, sDst, maxFull, invZ, hcb);
    hipLaunchKernelGGL(kAlpha,   dim3(2048), dim3(256), 0, stream, sSrc, sDst, maxFull, invZ, out1);
    hipLaunchKernelGGL(kMergeM,  dim3(128),  dim3(256), 0, stream, hcb, mw, mbv, out0);
}